// Round 1
// baseline (976.572 us; speedup 1.0000x reference)
//
#include <hip/hip_runtime.h>
#include <hip/hip_bf16.h>
#include <cstdint>

#define DM 2048
#define DF 8192
#define MTOK 16384  // 4*4096 tokens

typedef int v4i __attribute__((ext_vector_type(4)));

__device__ __forceinline__ float silu_f(float y) {
  // y * sigmoid(y); same expression used in GEMM1 epilogue and quant_h so the
  // bits match exactly (no fma-contraction pattern present).
  return y * (1.0f / (1.0f + expf(-y)));
}

__device__ __forceinline__ void gload_lds16(const void* g, void* l) {
  __builtin_amdgcn_global_load_lds(
      (const __attribute__((address_space(1))) void*)g,
      (__attribute__((address_space(3))) void*)l, 16, 0, 0);
}

// ---- stage 1: sum |w| partials (deterministic fixed-order tree) ----
__global__ __launch_bounds__(256) void abs_sum_k(const float* __restrict__ w,
                                                 float* __restrict__ partial) {
  const int t = threadIdx.x;
  const float4* wp = (const float4*)w;
  const long base = (long)blockIdx.x * 4096;  // float4 units; 1024 blocks x 16384 floats
  float s = 0.f;
#pragma unroll
  for (int i = 0; i < 16; ++i) {
    float4 v = wp[base + i * 256 + t];
    s += fabsf(v.x) + fabsf(v.y) + fabsf(v.z) + fabsf(v.w);
  }
#pragma unroll
  for (int d = 1; d < 64; d <<= 1) s += __shfl_xor(s, d, 64);
  __shared__ float wsum[4];
  if ((t & 63) == 0) wsum[t >> 6] = s;
  __syncthreads();
  if (t == 0) partial[blockIdx.x] = (wsum[0] + wsum[1]) + (wsum[2] + wsum[3]);
}

// ---- stage 2: finalize weight scales. sc[0]=sw1, sc[1]=1/sw1, sc[2]=sw2, sc[3]=1/sw2 ----
__global__ __launch_bounds__(256) void finalize_scales_k(const float* __restrict__ p1,
                                                         const float* __restrict__ p2,
                                                         float* __restrict__ sc) {
  const float* p = (blockIdx.x == 0) ? p1 : p2;
  const int t = threadIdx.x;
  float s = (p[t] + p[t + 256]) + (p[t + 512] + p[t + 768]);
#pragma unroll
  for (int d = 1; d < 64; d <<= 1) s += __shfl_xor(s, d, 64);
  __shared__ float wsum[4];
  if ((t & 63) == 0) wsum[t >> 6] = s;
  __syncthreads();
  if (t == 0) {
    float total = (wsum[0] + wsum[1]) + (wsum[2] + wsum[3]);
    float mean = total * (1.0f / 16777216.0f);  // exact /2^24
    float c = fmaxf(mean, 1e-5f);
    sc[blockIdx.x * 2 + 0] = 1.0f / c;  // scale applied to weights
    sc[blockIdx.x * 2 + 1] = c;         // inverse contribution (1/scale)
  }
}

// ---- ternary weight quantization: wq = clamp(rint(w*s), -1, 1) ----
__global__ __launch_bounds__(256) void tern_quant_k(const float* __restrict__ w,
                                                    int8_t* __restrict__ wq,
                                                    const float* __restrict__ scp) {
  const float s = scp[0];
  const long i = (long)blockIdx.x * 256 + threadIdx.x;  // float4 index
  float4 v = ((const float4*)w)[i];
  int q0 = (int)rintf(v.x * s); q0 = q0 < -1 ? -1 : (q0 > 1 ? 1 : q0);
  int q1 = (int)rintf(v.y * s); q1 = q1 < -1 ? -1 : (q1 > 1 ? 1 : q1);
  int q2 = (int)rintf(v.z * s); q2 = q2 < -1 ? -1 : (q2 > 1 ? 1 : q2);
  int q3 = (int)rintf(v.w * s); q3 = q3 < -1 ? -1 : (q3 > 1 ? 1 : q3);
  ((int*)wq)[i] = (q0 & 255) | ((q1 & 255) << 8) | ((q2 & 255) << 16) | ((q3 & 255) << 24);
}

// ---- per-token activation quant of x (row = 2048 fp32) ----
__global__ __launch_bounds__(256) void act_quant_x_k(const float* __restrict__ x,
                                                     int8_t* __restrict__ xq,
                                                     float* __restrict__ inv_sx) {
  const int t = threadIdx.x;
  const long row = blockIdx.x;
  const float4* xr = (const float4*)(x + row * DM);
  float4 v0 = xr[t * 2], v1 = xr[t * 2 + 1];
  float m = fmaxf(fmaxf(fmaxf(fabsf(v0.x), fabsf(v0.y)), fmaxf(fabsf(v0.z), fabsf(v0.w))),
                  fmaxf(fmaxf(fabsf(v1.x), fabsf(v1.y)), fmaxf(fabsf(v1.z), fabsf(v1.w))));
#pragma unroll
  for (int d = 1; d < 64; d <<= 1) m = fmaxf(m, __shfl_xor(m, d, 64));
  __shared__ float wm[4];
  if ((t & 63) == 0) wm[t >> 6] = m;
  __syncthreads();
  m = fmaxf(fmaxf(wm[0], wm[1]), fmaxf(wm[2], wm[3]));
  const float scale = 127.0f / fmaxf(m, 1e-5f);
  if (t == 0) inv_sx[row] = 1.0f / scale;
  float vv[8] = {v0.x, v0.y, v0.z, v0.w, v1.x, v1.y, v1.z, v1.w};
  int q[8];
#pragma unroll
  for (int j = 0; j < 8; ++j) {
    int qq = (int)rintf(vv[j] * scale);
    q[j] = qq < -128 ? -128 : (qq > 127 ? 127 : qq);
  }
  int lo = (q[0] & 255) | ((q[1] & 255) << 8) | ((q[2] & 255) << 16) | ((q[3] & 255) << 24);
  int hi = (q[4] & 255) | ((q[5] & 255) << 8) | ((q[6] & 255) << 16) | ((q[7] & 255) << 24);
  ((int2*)(xq + row * DM))[t] = make_int2(lo, hi);
}

// ---- int8 GEMM, C = A[M,K] * B[N,K]^T, 128x128 tile, BK=64, 4 waves 2x2 ----
// EPI==1: GEMM1 epilogue (store y int16 + per-(row,block) max|silu(y)| partials)
// EPI==0: GEMM2 epilogue (store fp32 out = acc * rowInv * invsw)
template <int K, int EPI>
__global__ __launch_bounds__(256) void gemm_i8_k(
    const int8_t* __restrict__ A, const int8_t* __restrict__ B,
    const float* __restrict__ rowInv, const float* __restrict__ invswp,
    short* __restrict__ Y16, float* __restrict__ rowmaxP,
    float* __restrict__ Out) {
  __shared__ int8_t As[8192];
  __shared__ int8_t Bs[8192];
  __shared__ float redmax[256];  // [128 rows][2 wc]

  const int t = threadIdx.x;
  const int wave = t >> 6;
  const int lane = t & 63;
  const int wr = wave >> 1, wc = wave & 1;
  const int l15 = lane & 15, l4 = lane >> 4;
  const long arow0 = (long)blockIdx.y * 128;
  const long brow0 = (long)blockIdx.x * 128;
  const int N = gridDim.x * 128;

  const int srow = t >> 2;            // staging row within 64-row half
  const int scolb = (t & 3) * 16;     // staging byte col within 64-wide K tile
  const int8_t* Abase = A + (arow0 + srow) * (long)K + scolb;
  const int8_t* Bbase = B + (brow0 + srow) * (long)K + scolb;

  v4i acc[4][4] = {};

  for (int kt = 0; kt < K; kt += 64) {
    gload_lds16(Abase + kt,                As + wave * 1024);
    gload_lds16(Abase + (long)64 * K + kt, As + 4096 + wave * 1024);
    gload_lds16(Bbase + kt,                Bs + wave * 1024);
    gload_lds16(Bbase + (long)64 * K + kt, Bs + 4096 + wave * 1024);
    __syncthreads();
    v4i af[4], bf[4];
#pragma unroll
    for (int mi = 0; mi < 4; ++mi)
      af[mi] = *(const v4i*)(As + (wr * 64 + mi * 16 + l15) * 64 + l4 * 16);
#pragma unroll
    for (int ni = 0; ni < 4; ++ni)
      bf[ni] = *(const v4i*)(Bs + (wc * 64 + ni * 16 + l15) * 64 + l4 * 16);
#pragma unroll
    for (int mi = 0; mi < 4; ++mi)
#pragma unroll
      for (int ni = 0; ni < 4; ++ni)
        acc[mi][ni] = __builtin_amdgcn_mfma_i32_16x16x64_i8(af[mi], bf[ni], acc[mi][ni], 0, 0, 0);
    __syncthreads();
  }

  const float invsw = invswp[0];
  if constexpr (EPI == 1) {
#pragma unroll
    for (int mi = 0; mi < 4; ++mi) {
#pragma unroll
      for (int r = 0; r < 4; ++r) {
        const int lrow = wr * 64 + mi * 16 + l4 * 4 + r;
        const long grow = arow0 + lrow;
        const float c1 = rowInv[grow] * invsw;
        float mx = 0.f;
#pragma unroll
        for (int ni = 0; ni < 4; ++ni) {
          int yi = acc[mi][ni][r];
          float h = silu_f((float)yi * c1);
          mx = fmaxf(mx, fabsf(h));
          int ys = yi < -32767 ? -32767 : (yi > 32767 ? 32767 : yi);
          Y16[grow * DF + brow0 + wc * 64 + ni * 16 + l15] = (short)ys;
        }
#pragma unroll
        for (int d = 1; d < 16; d <<= 1) mx = fmaxf(mx, __shfl_xor(mx, d, 64));
        if (l15 == 0) redmax[lrow * 2 + wc] = mx;
      }
    }
    __syncthreads();
    if (t < 128) {
      float mm = fmaxf(redmax[t * 2], redmax[t * 2 + 1]);
      rowmaxP[(arow0 + t) * gridDim.x + blockIdx.x] = mm;
    }
  } else {
#pragma unroll
    for (int mi = 0; mi < 4; ++mi) {
#pragma unroll
      for (int r = 0; r < 4; ++r) {
        const long grow = arow0 + wr * 64 + mi * 16 + l4 * 4 + r;
        const float c2 = rowInv[grow] * invsw;
#pragma unroll
        for (int ni = 0; ni < 4; ++ni)
          Out[grow * N + brow0 + wc * 64 + ni * 16 + l15] = (float)acc[mi][ni][r] * c2;
      }
    }
  }
}

// ---- quantize h = silu(y*c1) per-token from int16 y, using rowmax partials ----
__global__ __launch_bounds__(256) void quant_h_k(const short* __restrict__ Y16,
                                                 const float* __restrict__ rowmaxP,
                                                 const float* __restrict__ inv_sx,
                                                 const float* __restrict__ sc,
                                                 int8_t* __restrict__ hq,
                                                 float* __restrict__ inv_sh) {
  const int t = threadIdx.x;
  const long row = blockIdx.x;
  __shared__ float smax_s;
  if (t < 64) {
    float m = rowmaxP[row * 64 + t];
#pragma unroll
    for (int d = 1; d < 64; d <<= 1) m = fmaxf(m, __shfl_xor(m, d, 64));
    if (t == 0) smax_s = m;
  }
  __syncthreads();
  const float scale = 127.0f / fmaxf(smax_s, 1e-5f);
  if (t == 0) inv_sh[row] = 1.0f / scale;
  const float c1 = inv_sx[row] * sc[1];
  const short4* yp = (const short4*)(Y16 + row * DF);
  int* op = (int*)(hq + row * DF);
#pragma unroll
  for (int b = 0; b < 8; ++b) {
    short4 s4 = yp[b * 256 + t];
    short vals[4] = {s4.x, s4.y, s4.z, s4.w};
    int q[4];
#pragma unroll
    for (int j = 0; j < 4; ++j) {
      float h = silu_f((float)vals[j] * c1);
      int qq = (int)rintf(h * scale);
      q[j] = qq < -128 ? -128 : (qq > 127 ? 127 : qq);
    }
    op[b * 256 + t] = (q[0] & 255) | ((q[1] & 255) << 8) | ((q[2] & 255) << 16) | ((q[3] & 255) << 24);
  }
}

extern "C" void kernel_launch(void* const* d_in, const int* in_sizes, int n_in,
                              void* d_out, int out_size, void* d_ws, size_t ws_size,
                              hipStream_t stream) {
  const float* x = (const float*)d_in[0];
  const float* W1 = (const float*)d_in[1];
  const float* W2 = (const float*)d_in[2];
  float* out = (float*)d_out;

  uint8_t* w = (uint8_t*)d_ws;
  float* sc = (float*)(w + 0);                  // 4 floats
  float* p1 = (float*)(w + 256);                // 1024 floats
  float* p2 = (float*)(w + 256 + 4096);         // 1024 floats
  float* inv_sx = (float*)(w + 8448);           // 16384 floats
  float* inv_sh = (float*)(w + 8448 + 65536);   // 16384 floats
  float* rowmaxP = (float*)(w + 8448 + 131072); // 16384*64 floats (4 MB)
  uint8_t* w1q = w + 8448 + 131072 + 4194304;   // 16 MB
  uint8_t* w2q = w1q + 16777216;                // 16 MB
  uint8_t* xq = w2q + 16777216;                 // 32 MB
  uint8_t* hq = xq + 33554432;                  // 128 MB
  short* y16 = (short*)(hq + 134217728);        // 256 MB

  abs_sum_k<<<1024, 256, 0, stream>>>(W1, p1);
  abs_sum_k<<<1024, 256, 0, stream>>>(W2, p2);
  finalize_scales_k<<<2, 256, 0, stream>>>(p1, p2, sc);
  tern_quant_k<<<16384, 256, 0, stream>>>(W1, (int8_t*)w1q, sc + 0);
  tern_quant_k<<<16384, 256, 0, stream>>>(W2, (int8_t*)w2q, sc + 2);
  act_quant_x_k<<<16384, 256, 0, stream>>>(x, (int8_t*)xq, inv_sx);
  gemm_i8_k<2048, 1><<<dim3(64, 128), 256, 0, stream>>>(
      (const int8_t*)xq, (const int8_t*)w1q, inv_sx, sc + 1, y16, rowmaxP, nullptr);
  quant_h_k<<<16384, 256, 0, stream>>>(y16, rowmaxP, inv_sx, sc, (int8_t*)hq, inv_sh);
  gemm_i8_k<8192, 0><<<dim3(16, 128), 256, 0, stream>>>(
      (const int8_t*)hq, (const int8_t*)w2q, inv_sh, sc + 3, nullptr, nullptr, out);
}

// Round 2
// 834.083 us; speedup vs baseline: 1.1708x; 1.1708x over previous
//
#include <hip/hip_runtime.h>
#include <hip/hip_bf16.h>
#include <cstdint>

#define DM 2048
#define DF 8192

typedef int v4i __attribute__((ext_vector_type(4)));

__device__ __forceinline__ float silu_f(float y) {
  // y * sigmoid(y); identical expression in GEMM1 epilogue and quant_h.
  return y * (1.0f / (1.0f + expf(-y)));
}

__device__ __forceinline__ void gload_lds16(const void* g, void* l) {
  __builtin_amdgcn_global_load_lds(
      (const __attribute__((address_space(1))) void*)g,
      (__attribute__((address_space(3))) void*)l, 16, 0, 0);
}

// ---- stage 1: sum |w| partials (deterministic fixed-order tree) ----
__global__ __launch_bounds__(256) void abs_sum_k(const float* __restrict__ w,
                                                 float* __restrict__ partial) {
  const int t = threadIdx.x;
  const float4* wp = (const float4*)w;
  const long base = (long)blockIdx.x * 4096;
  float s = 0.f;
#pragma unroll
  for (int i = 0; i < 16; ++i) {
    float4 v = wp[base + i * 256 + t];
    s += fabsf(v.x) + fabsf(v.y) + fabsf(v.z) + fabsf(v.w);
  }
#pragma unroll
  for (int d = 1; d < 64; d <<= 1) s += __shfl_xor(s, d, 64);
  __shared__ float wsum[4];
  if ((t & 63) == 0) wsum[t >> 6] = s;
  __syncthreads();
  if (t == 0) partial[blockIdx.x] = (wsum[0] + wsum[1]) + (wsum[2] + wsum[3]);
}

// ---- stage 2: finalize weight scales. sc[0]=sw1, sc[1]=1/sw1, sc[2]=sw2, sc[3]=1/sw2 ----
__global__ __launch_bounds__(256) void finalize_scales_k(const float* __restrict__ p1,
                                                         const float* __restrict__ p2,
                                                         float* __restrict__ sc) {
  const float* p = (blockIdx.x == 0) ? p1 : p2;
  const int t = threadIdx.x;
  float s = (p[t] + p[t + 256]) + (p[t + 512] + p[t + 768]);
#pragma unroll
  for (int d = 1; d < 64; d <<= 1) s += __shfl_xor(s, d, 64);
  __shared__ float wsum[4];
  if ((t & 63) == 0) wsum[t >> 6] = s;
  __syncthreads();
  if (t == 0) {
    float total = (wsum[0] + wsum[1]) + (wsum[2] + wsum[3]);
    float mean = total * (1.0f / 16777216.0f);
    float c = fmaxf(mean, 1e-5f);
    sc[blockIdx.x * 2 + 0] = 1.0f / c;
    sc[blockIdx.x * 2 + 1] = c;
  }
}

// ---- ternary weight quantization ----
__global__ __launch_bounds__(256) void tern_quant_k(const float* __restrict__ w,
                                                    int8_t* __restrict__ wq,
                                                    const float* __restrict__ scp) {
  const float s = scp[0];
  const long i = (long)blockIdx.x * 256 + threadIdx.x;
  float4 v = ((const float4*)w)[i];
  int q0 = (int)rintf(v.x * s); q0 = q0 < -1 ? -1 : (q0 > 1 ? 1 : q0);
  int q1 = (int)rintf(v.y * s); q1 = q1 < -1 ? -1 : (q1 > 1 ? 1 : q1);
  int q2 = (int)rintf(v.z * s); q2 = q2 < -1 ? -1 : (q2 > 1 ? 1 : q2);
  int q3 = (int)rintf(v.w * s); q3 = q3 < -1 ? -1 : (q3 > 1 ? 1 : q3);
  ((int*)wq)[i] = (q0 & 255) | ((q1 & 255) << 8) | ((q2 & 255) << 16) | ((q3 & 255) << 24);
}

// ---- per-token activation quant of x ----
__global__ __launch_bounds__(256) void act_quant_x_k(const float* __restrict__ x,
                                                     int8_t* __restrict__ xq,
                                                     float* __restrict__ inv_sx) {
  const int t = threadIdx.x;
  const long row = blockIdx.x;
  const float4* xr = (const float4*)(x + row * DM);
  float4 v0 = xr[t * 2], v1 = xr[t * 2 + 1];
  float m = fmaxf(fmaxf(fmaxf(fabsf(v0.x), fabsf(v0.y)), fmaxf(fabsf(v0.z), fabsf(v0.w))),
                  fmaxf(fmaxf(fabsf(v1.x), fabsf(v1.y)), fmaxf(fabsf(v1.z), fabsf(v1.w))));
#pragma unroll
  for (int d = 1; d < 64; d <<= 1) m = fmaxf(m, __shfl_xor(m, d, 64));
  __shared__ float wm[4];
  if ((t & 63) == 0) wm[t >> 6] = m;
  __syncthreads();
  m = fmaxf(fmaxf(wm[0], wm[1]), fmaxf(wm[2], wm[3]));
  const float scale = 127.0f / fmaxf(m, 1e-5f);
  if (t == 0) inv_sx[row] = 1.0f / scale;
  float vv[8] = {v0.x, v0.y, v0.z, v0.w, v1.x, v1.y, v1.z, v1.w};
  int q[8];
#pragma unroll
  for (int j = 0; j < 8; ++j) {
    int qq = (int)rintf(vv[j] * scale);
    q[j] = qq < -128 ? -128 : (qq > 127 ? 127 : qq);
  }
  int lo = (q[0] & 255) | ((q[1] & 255) << 8) | ((q[2] & 255) << 16) | ((q[3] & 255) << 24);
  int hi = (q[4] & 255) | ((q[5] & 255) << 8) | ((q[6] & 255) << 16) | ((q[7] & 255) << 24);
  ((int2*)(xq + row * DM))[t] = make_int2(lo, hi);
}

// ---- int8 GEMM, 256x256 tile, BK=128 bytes, 8-phase schedule (T1+T2+T3+T4+T5) ----
// C = A[M,K] * B[N,K]^T. 8 waves (2M x 4N), per-wave C = 128x64.
// LDS: 2 dbuf x (A 32KB + B 32KB) = 128KB. XOR-swizzle (row&7)<<4 on byte col,
// applied on the global_load_lds SOURCE and on the ds_read address (rule #21).
template <int K, int N, int EPI>
__global__ __launch_bounds__(512, 2) void gemm8_i8_k(
    const int8_t* __restrict__ A, const int8_t* __restrict__ B,
    const float* __restrict__ rowInv, const float* __restrict__ invswp,
    short* __restrict__ Y16, float* __restrict__ rowmaxP,
    float* __restrict__ Out) {
  constexpr int NT = K / 128;
  constexpr int NBX = N / 256;
  __shared__ __align__(16) uint8_t lds[131072];

  const int t = threadIdx.x;
  const int wave = t >> 6;
  const int lane = t & 63;
  const int wr = wave >> 2;   // 0..1 (M half)
  const int wc = wave & 3;    // 0..3 (N quarter)
  const int l15 = lane & 15, l4 = lane >> 4;

  // bijective XCD swizzle (gridDim.x % 8 == 0 for both GEMMs)
  const int cpx = (int)gridDim.x >> 3;
  const int bid0 = blockIdx.x;
  const int bid = (bid0 & 7) * cpx + (bid0 >> 3);
  const int bx = bid % NBX, by = bid / NBX;
  const long arow0 = (long)by * 256;
  const long bcol0 = (long)bx * 256;

  const int8_t* Ablk = A + arow0 * K;
  const int8_t* Bblk = B + bcol0 * K;

  // staging constants: thread t covers physical (row=t>>3, colgroup=t&7) of a
  // 64-row sub-issue; source col pre-swizzled so linear LDS dest is swizzled.
  const int srow = t >> 3;
  const int scol = ((t & 7) ^ (srow & 7)) << 4;

  // fragment-read constants (row&7 == l15&7 for all mi/ni)
  const int rAo = (wr * 128 + l15) * 128;
  const int rBo = (wc * 64 + l15) * 128;
  const int sw = (l15 & 7) << 4;
  const int cc0 = (l4 * 16) ^ sw;          // k-slice 0
  const int cc1 = (64 | (l4 * 16)) ^ sw;   // k-slice 1

  v4i acc[8][4] = {};
  v4i a[8][2], b[4][2];

#define STAGEHT(ht_)                                                             \
  do {                                                                           \
    const int ht = (ht_);                                                        \
    if (ht < 4 * NT) {                                                           \
      const int kts = ht >> 2, part = ht & 3;                                    \
      uint8_t* d0 = lds + ((kts & 1) << 16) + (part << 14) + (wave << 10);       \
      const int8_t* sp = (part < 2) ? Ablk : Bblk;                               \
      const int8_t* s0 =                                                         \
          sp + (long)(((part & 1) << 7) + srow) * K + ((long)kts << 7) + scol;   \
      gload_lds16(s0, d0);                                                       \
      gload_lds16(s0 + ((long)K << 6), d0 + 8192);                               \
    }                                                                            \
  } while (0)

#define BAR1()                                              \
  asm volatile("" ::: "memory");                            \
  __builtin_amdgcn_s_barrier();                             \
  asm volatile("s_waitcnt lgkmcnt(0)" ::: "memory")

#define BAR2()                                              \
  asm volatile("" ::: "memory");                            \
  __builtin_amdgcn_s_barrier()

#define MM(mi, ni)                                                                          \
  acc[mi][ni] = __builtin_amdgcn_mfma_i32_16x16x64_i8(a[mi][0], b[ni][0], acc[mi][ni], 0, 0, 0); \
  acc[mi][ni] = __builtin_amdgcn_mfma_i32_16x16x64_i8(a[mi][1], b[ni][1], acc[mi][ni], 0, 0, 0)

  // prologue: stage K0 fully (ht0-3) + K1 h0..h2 (ht4-6); keep 3 half-tiles in flight
  STAGEHT(0); STAGEHT(1); STAGEHT(2); STAGEHT(3);
  STAGEHT(4); STAGEHT(5); STAGEHT(6);
  asm volatile("s_waitcnt vmcnt(6)" ::: "memory");
  __builtin_amdgcn_s_barrier();

  for (int kt = 0; kt < NT; ++kt) {
    const uint8_t* sA = lds + ((kt & 1) << 16);
    const uint8_t* sB = sA + 32768;

    // ---- phase 0: read A mi0-3 + B ni0-1 (12 ds_read); stage K(kt+1).Bh1
    #pragma unroll
    for (int mi = 0; mi < 4; ++mi) {
      a[mi][0] = *(const v4i*)(sA + rAo + mi * 2048 + cc0);
      a[mi][1] = *(const v4i*)(sA + rAo + mi * 2048 + cc1);
    }
    #pragma unroll
    for (int ni = 0; ni < 2; ++ni) {
      b[ni][0] = *(const v4i*)(sB + rBo + ni * 2048 + cc0);
      b[ni][1] = *(const v4i*)(sB + rBo + ni * 2048 + cc1);
    }
    STAGEHT(4 * kt + 7);
    BAR1();
    __builtin_amdgcn_s_setprio(1);
    MM(0, 0); MM(0, 1); MM(1, 0); MM(1, 1);
    MM(2, 0); MM(2, 1); MM(3, 0); MM(3, 1);
    __builtin_amdgcn_s_setprio(0);
    BAR2();

    // ---- phase 1: read A mi4-7 (8 ds_read); stage K(kt+2).Ah0
    #pragma unroll
    for (int mi = 4; mi < 8; ++mi) {
      a[mi][0] = *(const v4i*)(sA + rAo + mi * 2048 + cc0);
      a[mi][1] = *(const v4i*)(sA + rAo + mi * 2048 + cc1);
    }
    STAGEHT(4 * kt + 8);
    BAR1();
    __builtin_amdgcn_s_setprio(1);
    MM(4, 0); MM(4, 1); MM(5, 0); MM(5, 1);
    MM(6, 0); MM(6, 1); MM(7, 0); MM(7, 1);
    __builtin_amdgcn_s_setprio(0);
    BAR2();

    // ---- phase 2: read B ni2-3 (4 ds_read); stage K(kt+2).Ah1
    #pragma unroll
    for (int ni = 2; ni < 4; ++ni) {
      b[ni][0] = *(const v4i*)(sB + rBo + ni * 2048 + cc0);
      b[ni][1] = *(const v4i*)(sB + rBo + ni * 2048 + cc1);
    }
    STAGEHT(4 * kt + 9);
    BAR1();
    __builtin_amdgcn_s_setprio(1);
    MM(0, 2); MM(0, 3); MM(1, 2); MM(1, 3);
    MM(2, 2); MM(2, 3); MM(3, 2); MM(3, 3);
    __builtin_amdgcn_s_setprio(0);
    BAR2();

    // ---- phase 3: no ds_read; stage K(kt+2).Bh0; counted vmcnt once per K-tile
    STAGEHT(4 * kt + 10);
    BAR2();  // phase-start barrier (no lgkm wait needed)
    __builtin_amdgcn_s_setprio(1);
    MM(4, 2); MM(4, 3); MM(5, 2); MM(5, 3);
    MM(6, 2); MM(6, 3); MM(7, 2); MM(7, 3);
    __builtin_amdgcn_s_setprio(0);
    if (kt < NT - 2) {
      asm volatile("s_waitcnt vmcnt(6)" ::: "memory");
    } else if (kt == NT - 2) {
      asm volatile("s_waitcnt vmcnt(0)" ::: "memory");
    }
    BAR2();
  }

  const float invsw = invswp[0];
  if constexpr (EPI == 1) {
    __syncthreads();  // full drain before LDS reuse
    float* redmax = (float*)lds;  // [256 rows][4 wc]
#pragma unroll
    for (int mi = 0; mi < 8; ++mi) {
#pragma unroll
      for (int r = 0; r < 4; ++r) {
        const int lrow = wr * 128 + mi * 16 + l4 * 4 + r;
        const long grow = arow0 + lrow;
        const float c1v = rowInv[grow] * invsw;
        float mx = 0.f;
#pragma unroll
        for (int ni = 0; ni < 4; ++ni) {
          int yi = acc[mi][ni][r];
          float h = silu_f((float)yi * c1v);
          mx = fmaxf(mx, fabsf(h));
          int ys = yi < -32767 ? -32767 : (yi > 32767 ? 32767 : yi);
          Y16[grow * (long)DF + bcol0 + wc * 64 + ni * 16 + l15] = (short)ys;
        }
#pragma unroll
        for (int d = 1; d < 16; d <<= 1) mx = fmaxf(mx, __shfl_xor(mx, d, 64));
        if (l15 == 0) redmax[lrow * 4 + wc] = mx;
      }
    }
    __syncthreads();
    if (t < 256) {
      float mm = fmaxf(fmaxf(redmax[t * 4], redmax[t * 4 + 1]),
                       fmaxf(redmax[t * 4 + 2], redmax[t * 4 + 3]));
      rowmaxP[(arow0 + t) * NBX + bx] = mm;
    }
  } else {
#pragma unroll
    for (int mi = 0; mi < 8; ++mi) {
#pragma unroll
      for (int r = 0; r < 4; ++r) {
        const long grow = arow0 + wr * 128 + mi * 16 + l4 * 4 + r;
        const float c2 = rowInv[grow] * invsw;
#pragma unroll
        for (int ni = 0; ni < 4; ++ni)
          Out[grow * N + bcol0 + wc * 64 + ni * 16 + l15] = (float)acc[mi][ni][r] * c2;
      }
    }
  }
#undef STAGEHT
#undef BAR1
#undef BAR2
#undef MM
}

// ---- quantize h = silu(y*c1) per-token from int16 y, using rowmax partials ----
__global__ __launch_bounds__(256) void quant_h_k(const short* __restrict__ Y16,
                                                 const float* __restrict__ rowmaxP,
                                                 const float* __restrict__ inv_sx,
                                                 const float* __restrict__ sc,
                                                 int8_t* __restrict__ hq,
                                                 float* __restrict__ inv_sh) {
  const int t = threadIdx.x;
  const long row = blockIdx.x;
  __shared__ float smax_s;
  if (t < 64) {
    float m = (t < 32) ? rowmaxP[row * 32 + t] : 0.f;
#pragma unroll
    for (int d = 1; d < 64; d <<= 1) m = fmaxf(m, __shfl_xor(m, d, 64));
    if (t == 0) smax_s = m;
  }
  __syncthreads();
  const float scale = 127.0f / fmaxf(smax_s, 1e-5f);
  if (t == 0) inv_sh[row] = 1.0f / scale;
  const float c1 = inv_sx[row] * sc[1];
  const short4* yp = (const short4*)(Y16 + row * DF);
  int* op = (int*)(hq + row * DF);
#pragma unroll
  for (int b = 0; b < 8; ++b) {
    short4 s4 = yp[b * 256 + t];
    short vals[4] = {s4.x, s4.y, s4.z, s4.w};
    int q[4];
#pragma unroll
    for (int j = 0; j < 4; ++j) {
      float h = silu_f((float)vals[j] * c1);
      int qq = (int)rintf(h * scale);
      q[j] = qq < -128 ? -128 : (qq > 127 ? 127 : qq);
    }
    op[b * 256 + t] = (q[0] & 255) | ((q[1] & 255) << 8) | ((q[2] & 255) << 16) | ((q[3] & 255) << 24);
  }
}

extern "C" void kernel_launch(void* const* d_in, const int* in_sizes, int n_in,
                              void* d_out, int out_size, void* d_ws, size_t ws_size,
                              hipStream_t stream) {
  const float* x = (const float*)d_in[0];
  const float* W1 = (const float*)d_in[1];
  const float* W2 = (const float*)d_in[2];
  float* out = (float*)d_out;

  uint8_t* w = (uint8_t*)d_ws;
  float* sc = (float*)(w + 0);                  // 4 floats
  float* p1 = (float*)(w + 256);                // 1024 floats
  float* p2 = (float*)(w + 256 + 4096);         // 1024 floats
  float* inv_sx = (float*)(w + 8448);           // 16384 floats
  float* inv_sh = (float*)(w + 8448 + 65536);   // 16384 floats
  float* rowmaxP = (float*)(w + 8448 + 131072); // 16384*32 floats (2 MB used of 4 MB slot)
  uint8_t* w1q = w + 8448 + 131072 + 4194304;   // 16 MB
  uint8_t* w2q = w1q + 16777216;                // 16 MB
  uint8_t* xq = w2q + 16777216;                 // 32 MB
  uint8_t* hq = xq + 33554432;                  // 128 MB
  short* y16 = (short*)(hq + 134217728);        // 256 MB

  abs_sum_k<<<1024, 256, 0, stream>>>(W1, p1);
  abs_sum_k<<<1024, 256, 0, stream>>>(W2, p2);
  finalize_scales_k<<<2, 256, 0, stream>>>(p1, p2, sc);
  tern_quant_k<<<16384, 256, 0, stream>>>(W1, (int8_t*)w1q, sc + 0);
  tern_quant_k<<<16384, 256, 0, stream>>>(W2, (int8_t*)w2q, sc + 2);
  act_quant_x_k<<<16384, 256, 0, stream>>>(x, (int8_t*)xq, inv_sx);
  // GEMM1: [16384,2048] x [8192,2048]^T -> y16 + rowmax partials. grid 64*32=2048
  gemm8_i8_k<2048, 8192, 1><<<2048, 512, 0, stream>>>(
      (const int8_t*)xq, (const int8_t*)w1q, inv_sx, sc + 1, y16, rowmaxP, nullptr);
  quant_h_k<<<16384, 256, 0, stream>>>(y16, rowmaxP, inv_sx, sc, (int8_t*)hq, inv_sh);
  // GEMM2: [16384,8192] x [2048,8192]^T -> out. grid 64*8=512
  gemm8_i8_k<8192, 2048, 0><<<512, 512, 0, stream>>>(
      (const int8_t*)hq, (const int8_t*)w2q, inv_sh, sc + 3, nullptr, nullptr, out);
}

// Round 3
// 820.540 us; speedup vs baseline: 1.1902x; 1.0165x over previous
//
#include <hip/hip_runtime.h>
#include <hip/hip_bf16.h>
#include <cstdint>

#define DM 2048
#define DF 8192

typedef int v4i __attribute__((ext_vector_type(4)));

__device__ __forceinline__ float silu_f(float y) {
  return y * (1.0f / (1.0f + expf(-y)));
}

__device__ __forceinline__ void gload_lds16(const void* g, void* l) {
  __builtin_amdgcn_global_load_lds(
      (const __attribute__((address_space(1))) void*)g,
      (__attribute__((address_space(3))) void*)l, 16, 0, 0);
}

// ---- stage 1: sum |w| partials ----
__global__ __launch_bounds__(256) void abs_sum_k(const float* __restrict__ w,
                                                 float* __restrict__ partial) {
  const int t = threadIdx.x;
  const float4* wp = (const float4*)w;
  const long base = (long)blockIdx.x * 4096;
  float s = 0.f;
#pragma unroll
  for (int i = 0; i < 16; ++i) {
    float4 v = wp[base + i * 256 + t];
    s += fabsf(v.x) + fabsf(v.y) + fabsf(v.z) + fabsf(v.w);
  }
#pragma unroll
  for (int d = 1; d < 64; d <<= 1) s += __shfl_xor(s, d, 64);
  __shared__ float wsum[4];
  if ((t & 63) == 0) wsum[t >> 6] = s;
  __syncthreads();
  if (t == 0) partial[blockIdx.x] = (wsum[0] + wsum[1]) + (wsum[2] + wsum[3]);
}

// ---- stage 2: finalize weight scales ----
__global__ __launch_bounds__(256) void finalize_scales_k(const float* __restrict__ p1,
                                                         const float* __restrict__ p2,
                                                         float* __restrict__ sc) {
  const float* p = (blockIdx.x == 0) ? p1 : p2;
  const int t = threadIdx.x;
  float s = (p[t] + p[t + 256]) + (p[t + 512] + p[t + 768]);
#pragma unroll
  for (int d = 1; d < 64; d <<= 1) s += __shfl_xor(s, d, 64);
  __shared__ float wsum[4];
  if ((t & 63) == 0) wsum[t >> 6] = s;
  __syncthreads();
  if (t == 0) {
    float total = (wsum[0] + wsum[1]) + (wsum[2] + wsum[3]);
    float mean = total * (1.0f / 16777216.0f);
    float c = fmaxf(mean, 1e-5f);
    sc[blockIdx.x * 2 + 0] = 1.0f / c;
    sc[blockIdx.x * 2 + 1] = c;
  }
}

// ---- ternary weight quantization ----
__global__ __launch_bounds__(256) void tern_quant_k(const float* __restrict__ w,
                                                    int8_t* __restrict__ wq,
                                                    const float* __restrict__ scp) {
  const float s = scp[0];
  const long i = (long)blockIdx.x * 256 + threadIdx.x;
  float4 v = ((const float4*)w)[i];
  int q0 = (int)rintf(v.x * s); q0 = q0 < -1 ? -1 : (q0 > 1 ? 1 : q0);
  int q1 = (int)rintf(v.y * s); q1 = q1 < -1 ? -1 : (q1 > 1 ? 1 : q1);
  int q2 = (int)rintf(v.z * s); q2 = q2 < -1 ? -1 : (q2 > 1 ? 1 : q2);
  int q3 = (int)rintf(v.w * s); q3 = q3 < -1 ? -1 : (q3 > 1 ? 1 : q3);
  ((int*)wq)[i] = (q0 & 255) | ((q1 & 255) << 8) | ((q2 & 255) << 16) | ((q3 & 255) << 24);
}

// ---- per-token activation quant of x ----
__global__ __launch_bounds__(256) void act_quant_x_k(const float* __restrict__ x,
                                                     int8_t* __restrict__ xq,
                                                     float* __restrict__ inv_sx) {
  const int t = threadIdx.x;
  const long row = blockIdx.x;
  const float4* xr = (const float4*)(x + row * DM);
  float4 v0 = xr[t * 2], v1 = xr[t * 2 + 1];
  float m = fmaxf(fmaxf(fmaxf(fabsf(v0.x), fabsf(v0.y)), fmaxf(fabsf(v0.z), fabsf(v0.w))),
                  fmaxf(fmaxf(fabsf(v1.x), fabsf(v1.y)), fmaxf(fabsf(v1.z), fabsf(v1.w))));
#pragma unroll
  for (int d = 1; d < 64; d <<= 1) m = fmaxf(m, __shfl_xor(m, d, 64));
  __shared__ float wm[4];
  if ((t & 63) == 0) wm[t >> 6] = m;
  __syncthreads();
  m = fmaxf(fmaxf(wm[0], wm[1]), fmaxf(wm[2], wm[3]));
  const float scale = 127.0f / fmaxf(m, 1e-5f);
  if (t == 0) inv_sx[row] = 1.0f / scale;
  float vv[8] = {v0.x, v0.y, v0.z, v0.w, v1.x, v1.y, v1.z, v1.w};
  int q[8];
#pragma unroll
  for (int j = 0; j < 8; ++j) {
    int qq = (int)rintf(vv[j] * scale);
    q[j] = qq < -128 ? -128 : (qq > 127 ? 127 : qq);
  }
  int lo = (q[0] & 255) | ((q[1] & 255) << 8) | ((q[2] & 255) << 16) | ((q[3] & 255) << 24);
  int hi = (q[4] & 255) | ((q[5] & 255) << 8) | ((q[6] & 255) << 16) | ((q[7] & 255) << 24);
  ((int2*)(xq + row * DM))[t] = make_int2(lo, hi);
}

// ---- cluster: 16 MFMA (4m x 2n x 2ks), ks-outer so same-acc writes are 8 apart
template <int MO, int NO>
__device__ __forceinline__ void cluster(const v4i (&af)[4][2], const v4i (&bf)[2][2],
                                        v4i (&acc)[8][4]) {
  __builtin_amdgcn_s_setprio(1);
#pragma unroll
  for (int ks = 0; ks < 2; ++ks)
#pragma unroll
    for (int m = 0; m < 4; ++m)
#pragma unroll
      for (int n = 0; n < 2; ++n)
        acc[MO + m][NO + n] = __builtin_amdgcn_mfma_i32_16x16x64_i8(
            af[m][ks], bf[n][ks], acc[MO + m][NO + n], 0, 0, 0);
  __builtin_amdgcn_s_setprio(0);
}

// ---- int8 GEMM, 256x256 tile, BK=128B, register-pipelined cluster schedule ----
// Per K-tile: 4 clusters Q0..Q3; ds_reads for Q(c+1) issued before Q(c)'s MFMAs.
// 2 barriers/K-tile: mid (A-region restage safety) + boundary (B safety + buffer flip).
// vmcnt(4) once per K-tile (leaves next-next A-tile stages in flight).
template <int K, int N, int EPI>
__global__ __launch_bounds__(512, 2) void gemm8_i8_k(
    const int8_t* __restrict__ A, const int8_t* __restrict__ B,
    const float* __restrict__ rowInv, const float* __restrict__ invswp,
    short* __restrict__ Y16, float* __restrict__ rowmaxP,
    float* __restrict__ Out) {
  constexpr int NT = K / 128;
  constexpr int NBX = N / 256;
  __shared__ __align__(16) uint8_t lds[131072];

  const int t = threadIdx.x;
  const int wave = t >> 6;
  const int lane = t & 63;
  const int wr = wave >> 2;   // 0..1
  const int wc = wave & 3;    // 0..3
  const int l15 = lane & 15, l4 = lane >> 4;

  const int cpx = (int)gridDim.x >> 3;
  const int bid0 = blockIdx.x;
  const int bid = (bid0 & 7) * cpx + (bid0 >> 3);
  const int bx = bid % NBX, by = bid / NBX;
  const long arow0 = (long)by * 256;
  const long bcol0 = (long)bx * 256;

  const int8_t* Ablk = A + arow0 * K;
  const int8_t* Bblk = B + bcol0 * K;

  const int srow = t >> 3;
  const int scol = ((t & 7) ^ (srow & 7)) << 4;

  const int rAo = (wr * 128 + l15) * 128;
  const int rBo = (wc * 64 + l15) * 128;
  const int sw = (l15 & 7) << 4;
  const int cc0 = (l4 * 16) ^ sw;
  const int cc1 = (64 | (l4 * 16)) ^ sw;

  v4i acc[8][4] = {};
  v4i a_lo[4][2], a_hi[4][2], b_lo[2][2], b_hi[2][2];

// parts: 0 = A rows 0-127, 1 = A rows 128-255, 2 = B rows 0-127, 3 = B rows 128-255
#define STAGE(ktile_, part_)                                                      \
  do {                                                                            \
    const int kk = (ktile_);                                                      \
    if (kk < NT) {                                                                \
      uint8_t* d0 = lds + ((kk & 1) << 16) + ((part_) << 14) + (wave << 10);      \
      const int8_t* sp = ((part_) < 2) ? Ablk : Bblk;                             \
      const int8_t* s0 =                                                          \
          sp + (long)((((part_) & 1) << 7) + srow) * K + ((long)kk << 7) + scol;  \
      gload_lds16(s0, d0);                                                        \
      gload_lds16(s0 + ((long)K << 6), d0 + 8192);                                \
    }                                                                             \
  } while (0)

#define LGKM0 asm volatile("s_waitcnt lgkmcnt(0)" ::: "memory"); \
              __builtin_amdgcn_sched_barrier(0)
#define SB    __builtin_amdgcn_sched_barrier(0)

  // prologue: K0 full + K1 A-halves; vmcnt(4) leaves K1.A in flight
  STAGE(0, 0); STAGE(0, 1); STAGE(0, 2); STAGE(0, 3);
  STAGE(1, 0); STAGE(1, 1);
  asm volatile("s_waitcnt vmcnt(4)" ::: "memory");
  __builtin_amdgcn_s_barrier();

  for (int kt = 0; kt < NT; ++kt) {
    const uint8_t* sA = lds + ((kt & 1) << 16);
    const uint8_t* sB = sA + 32768;

    // Q0 reads (12): a_lo + b_lo
#pragma unroll
    for (int m = 0; m < 4; ++m) {
      a_lo[m][0] = *(const v4i*)(sA + rAo + m * 2048 + cc0);
      a_lo[m][1] = *(const v4i*)(sA + rAo + m * 2048 + cc1);
    }
#pragma unroll
    for (int n = 0; n < 2; ++n) {
      b_lo[n][0] = *(const v4i*)(sB + rBo + n * 2048 + cc0);
      b_lo[n][1] = *(const v4i*)(sB + rBo + n * 2048 + cc1);
    }
    STAGE(kt + 1, 2);   // B0 -> other buffer (safe: prior reads ended last iter)
    LGKM0;
    // Q1 reads (8) issued before Q0's MFMAs: overlap LDS pipe with matrix pipe
#pragma unroll
    for (int m = 0; m < 4; ++m) {
      a_hi[m][0] = *(const v4i*)(sA + rAo + (m + 4) * 2048 + cc0);
      a_hi[m][1] = *(const v4i*)(sA + rAo + (m + 4) * 2048 + cc1);
    }
    STAGE(kt + 1, 3);   // B1 -> other buffer
    SB;
    cluster<0, 0>(a_lo, b_lo, acc);   // Q0
    LGKM0;
    // Q2 reads (4)
#pragma unroll
    for (int n = 0; n < 2; ++n) {
      b_hi[n][0] = *(const v4i*)(sB + rBo + (n + 2) * 2048 + cc0);
      b_hi[n][1] = *(const v4i*)(sB + rBo + (n + 2) * 2048 + cc1);
    }
    __builtin_amdgcn_s_barrier();     // A-safety: all waves' A reads complete
    STAGE(kt + 2, 0);   // A0 -> current buffer (safe after barrier)
    SB;
    cluster<4, 0>(a_hi, b_lo, acc);   // Q1
    LGKM0;
    STAGE(kt + 2, 1);   // A1 -> current buffer
    SB;
    cluster<0, 2>(a_lo, b_hi, acc);   // Q2
    cluster<4, 2>(a_hi, b_hi, acc);   // Q3 (no reads left this tile)
    if (kt < NT - 2) {
      asm volatile("s_waitcnt vmcnt(4)" ::: "memory");  // K(kt+1) resident; K(kt+2).A in flight
    } else if (kt == NT - 2) {
      asm volatile("s_waitcnt vmcnt(0)" ::: "memory");
    }
    __builtin_amdgcn_s_barrier();     // boundary
  }

  const float invsw = invswp[0];
  if constexpr (EPI == 1) {
    __syncthreads();
    float* redmax = (float*)lds;  // [256 rows][4 wc]
#pragma unroll
    for (int mi = 0; mi < 8; ++mi) {
#pragma unroll
      for (int r = 0; r < 4; ++r) {
        const int lrow = wr * 128 + mi * 16 + l4 * 4 + r;
        const long grow = arow0 + lrow;
        const float c1v = rowInv[grow] * invsw;
        float mx = 0.f;
#pragma unroll
        for (int ni = 0; ni < 4; ++ni) {
          int yi = acc[mi][ni][r];
          float h = silu_f((float)yi * c1v);
          mx = fmaxf(mx, fabsf(h));
          int ys = yi < -32767 ? -32767 : (yi > 32767 ? 32767 : yi);
          Y16[grow * (long)DF + bcol0 + wc * 64 + ni * 16 + l15] = (short)ys;
        }
#pragma unroll
        for (int d = 1; d < 16; d <<= 1) mx = fmaxf(mx, __shfl_xor(mx, d, 64));
        if (l15 == 0) redmax[lrow * 4 + wc] = mx;
      }
    }
    __syncthreads();
    if (t < 256) {
      float mm = fmaxf(fmaxf(redmax[t * 4], redmax[t * 4 + 1]),
                       fmaxf(redmax[t * 4 + 2], redmax[t * 4 + 3]));
      rowmaxP[(arow0 + t) * NBX + bx] = mm;
    }
  } else {
#pragma unroll
    for (int mi = 0; mi < 8; ++mi) {
#pragma unroll
      for (int r = 0; r < 4; ++r) {
        const long grow = arow0 + wr * 128 + mi * 16 + l4 * 4 + r;
        const float c2 = rowInv[grow] * invsw;
#pragma unroll
        for (int ni = 0; ni < 4; ++ni)
          Out[grow * N + bcol0 + wc * 64 + ni * 16 + l15] = (float)acc[mi][ni][r] * c2;
      }
    }
  }
#undef STAGE
#undef LGKM0
#undef SB
}

// ---- quantize h per-token from int16 y ----
__global__ __launch_bounds__(256) void quant_h_k(const short* __restrict__ Y16,
                                                 const float* __restrict__ rowmaxP,
                                                 const float* __restrict__ inv_sx,
                                                 const float* __restrict__ sc,
                                                 int8_t* __restrict__ hq,
                                                 float* __restrict__ inv_sh) {
  const int t = threadIdx.x;
  const long row = blockIdx.x;
  __shared__ float smax_s;
  if (t < 64) {
    float m = (t < 32) ? rowmaxP[row * 32 + t] : 0.f;
#pragma unroll
    for (int d = 1; d < 64; d <<= 1) m = fmaxf(m, __shfl_xor(m, d, 64));
    if (t == 0) smax_s = m;
  }
  __syncthreads();
  const float scale = 127.0f / fmaxf(smax_s, 1e-5f);
  if (t == 0) inv_sh[row] = 1.0f / scale;
  const float c1 = inv_sx[row] * sc[1];
  const short4* yp = (const short4*)(Y16 + row * DF);
  int* op = (int*)(hq + row * DF);
#pragma unroll
  for (int b = 0; b < 8; ++b) {
    short4 s4 = yp[b * 256 + t];
    short vals[4] = {s4.x, s4.y, s4.z, s4.w};
    int q[4];
#pragma unroll
    for (int j = 0; j < 4; ++j) {
      float h = silu_f((float)vals[j] * c1);
      int qq = (int)rintf(h * scale);
      q[j] = qq < -128 ? -128 : (qq > 127 ? 127 : qq);
    }
    op[b * 256 + t] = (q[0] & 255) | ((q[1] & 255) << 8) | ((q[2] & 255) << 16) | ((q[3] & 255) << 24);
  }
}

extern "C" void kernel_launch(void* const* d_in, const int* in_sizes, int n_in,
                              void* d_out, int out_size, void* d_ws, size_t ws_size,
                              hipStream_t stream) {
  const float* x = (const float*)d_in[0];
  const float* W1 = (const float*)d_in[1];
  const float* W2 = (const float*)d_in[2];
  float* out = (float*)d_out;

  uint8_t* w = (uint8_t*)d_ws;
  float* sc = (float*)(w + 0);
  float* p1 = (float*)(w + 256);
  float* p2 = (float*)(w + 256 + 4096);
  float* inv_sx = (float*)(w + 8448);
  float* inv_sh = (float*)(w + 8448 + 65536);
  float* rowmaxP = (float*)(w + 8448 + 131072);
  uint8_t* w1q = w + 8448 + 131072 + 4194304;
  uint8_t* w2q = w1q + 16777216;
  uint8_t* xq = w2q + 16777216;
  uint8_t* hq = xq + 33554432;
  short* y16 = (short*)(hq + 134217728);

  abs_sum_k<<<1024, 256, 0, stream>>>(W1, p1);
  abs_sum_k<<<1024, 256, 0, stream>>>(W2, p2);
  finalize_scales_k<<<2, 256, 0, stream>>>(p1, p2, sc);
  tern_quant_k<<<16384, 256, 0, stream>>>(W1, (int8_t*)w1q, sc + 0);
  tern_quant_k<<<16384, 256, 0, stream>>>(W2, (int8_t*)w2q, sc + 2);
  act_quant_x_k<<<16384, 256, 0, stream>>>(x, (int8_t*)xq, inv_sx);
  gemm8_i8_k<2048, 8192, 1><<<2048, 512, 0, stream>>>(
      (const int8_t*)xq, (const int8_t*)w1q, inv_sx, sc + 1, y16, rowmaxP, nullptr);
  quant_h_k<<<16384, 256, 0, stream>>>(y16, rowmaxP, inv_sx, sc, (int8_t*)hq, inv_sh);
  gemm8_i8_k<8192, 2048, 0><<<512, 512, 0, stream>>>(
      (const int8_t*)hq, (const int8_t*)w2q, inv_sh, sc + 3, nullptr, nullptr, out);
}

// Round 4
// 803.301 us; speedup vs baseline: 1.2157x; 1.0215x over previous
//
#include <hip/hip_runtime.h>
#include <hip/hip_bf16.h>
#include <cstdint>

#define DM 2048
#define DF 8192

typedef int v4i __attribute__((ext_vector_type(4)));
typedef short v8s __attribute__((ext_vector_type(8)));

__device__ __forceinline__ float silu_f(float y) {
  return y * (1.0f / (1.0f + expf(-y)));
}

__device__ __forceinline__ void gload_lds16(const void* g, void* l) {
  __builtin_amdgcn_global_load_lds(
      (const __attribute__((address_space(1))) void*)g,
      (__attribute__((address_space(3))) void*)l, 16, 0, 0);
}

// ---- stage 1: sum |w| partials ----
__global__ __launch_bounds__(256) void abs_sum_k(const float* __restrict__ w,
                                                 float* __restrict__ partial) {
  const int t = threadIdx.x;
  const float4* wp = (const float4*)w;
  const long base = (long)blockIdx.x * 4096;
  float s = 0.f;
#pragma unroll
  for (int i = 0; i < 16; ++i) {
    float4 v = wp[base + i * 256 + t];
    s += fabsf(v.x) + fabsf(v.y) + fabsf(v.z) + fabsf(v.w);
  }
#pragma unroll
  for (int d = 1; d < 64; d <<= 1) s += __shfl_xor(s, d, 64);
  __shared__ float wsum[4];
  if ((t & 63) == 0) wsum[t >> 6] = s;
  __syncthreads();
  if (t == 0) partial[blockIdx.x] = (wsum[0] + wsum[1]) + (wsum[2] + wsum[3]);
}

// ---- stage 2: finalize weight scales ----
__global__ __launch_bounds__(256) void finalize_scales_k(const float* __restrict__ p1,
                                                         const float* __restrict__ p2,
                                                         float* __restrict__ sc) {
  const float* p = (blockIdx.x == 0) ? p1 : p2;
  const int t = threadIdx.x;
  float s = (p[t] + p[t + 256]) + (p[t + 512] + p[t + 768]);
#pragma unroll
  for (int d = 1; d < 64; d <<= 1) s += __shfl_xor(s, d, 64);
  __shared__ float wsum[4];
  if ((t & 63) == 0) wsum[t >> 6] = s;
  __syncthreads();
  if (t == 0) {
    float total = (wsum[0] + wsum[1]) + (wsum[2] + wsum[3]);
    float mean = total * (1.0f / 16777216.0f);
    float c = fmaxf(mean, 1e-5f);
    sc[blockIdx.x * 2 + 0] = 1.0f / c;
    sc[blockIdx.x * 2 + 1] = c;
  }
}

// ---- ternary weight quantization ----
__global__ __launch_bounds__(256) void tern_quant_k(const float* __restrict__ w,
                                                    int8_t* __restrict__ wq,
                                                    const float* __restrict__ scp) {
  const float s = scp[0];
  const long i = (long)blockIdx.x * 256 + threadIdx.x;
  float4 v = ((const float4*)w)[i];
  int q0 = (int)rintf(v.x * s); q0 = q0 < -1 ? -1 : (q0 > 1 ? 1 : q0);
  int q1 = (int)rintf(v.y * s); q1 = q1 < -1 ? -1 : (q1 > 1 ? 1 : q1);
  int q2 = (int)rintf(v.z * s); q2 = q2 < -1 ? -1 : (q2 > 1 ? 1 : q2);
  int q3 = (int)rintf(v.w * s); q3 = q3 < -1 ? -1 : (q3 > 1 ? 1 : q3);
  ((int*)wq)[i] = (q0 & 255) | ((q1 & 255) << 8) | ((q2 & 255) << 16) | ((q3 & 255) << 24);
}

// ---- per-token activation quant of x ----
__global__ __launch_bounds__(256) void act_quant_x_k(const float* __restrict__ x,
                                                     int8_t* __restrict__ xq,
                                                     float* __restrict__ inv_sx) {
  const int t = threadIdx.x;
  const long row = blockIdx.x;
  const float4* xr = (const float4*)(x + row * DM);
  float4 v0 = xr[t * 2], v1 = xr[t * 2 + 1];
  float m = fmaxf(fmaxf(fmaxf(fabsf(v0.x), fabsf(v0.y)), fmaxf(fabsf(v0.z), fabsf(v0.w))),
                  fmaxf(fmaxf(fabsf(v1.x), fabsf(v1.y)), fmaxf(fabsf(v1.z), fabsf(v1.w))));
#pragma unroll
  for (int d = 1; d < 64; d <<= 1) m = fmaxf(m, __shfl_xor(m, d, 64));
  __shared__ float wm[4];
  if ((t & 63) == 0) wm[t >> 6] = m;
  __syncthreads();
  m = fmaxf(fmaxf(wm[0], wm[1]), fmaxf(wm[2], wm[3]));
  const float scale = 127.0f / fmaxf(m, 1e-5f);
  if (t == 0) inv_sx[row] = 1.0f / scale;
  float vv[8] = {v0.x, v0.y, v0.z, v0.w, v1.x, v1.y, v1.z, v1.w};
  int q[8];
#pragma unroll
  for (int j = 0; j < 8; ++j) {
    int qq = (int)rintf(vv[j] * scale);
    q[j] = qq < -128 ? -128 : (qq > 127 ? 127 : qq);
  }
  int lo = (q[0] & 255) | ((q[1] & 255) << 8) | ((q[2] & 255) << 16) | ((q[3] & 255) << 24);
  int hi = (q[4] & 255) | ((q[5] & 255) << 8) | ((q[6] & 255) << 16) | ((q[7] & 255) << 24);
  ((int2*)(xq + row * DM))[t] = make_int2(lo, hi);
}

// ---- cluster: 16 MFMA (4m x 2n x 2ks), ks-outer so same-acc writes are 8 apart
template <int MO, int NO>
__device__ __forceinline__ void cluster(const v4i (&af)[4][2], const v4i (&bf)[2][2],
                                        v4i (&acc)[8][4]) {
  __builtin_amdgcn_s_setprio(1);
#pragma unroll
  for (int ks = 0; ks < 2; ++ks)
#pragma unroll
    for (int m = 0; m < 4; ++m)
#pragma unroll
      for (int n = 0; n < 2; ++n)
        acc[MO + m][NO + n] = __builtin_amdgcn_mfma_i32_16x16x64_i8(
            af[m][ks], bf[n][ks], acc[MO + m][NO + n], 0, 0, 0);
  __builtin_amdgcn_s_setprio(0);
}

// ---- int8 GEMM, 256x256 tile, BK=128B, register-pipelined cluster schedule ----
// EPI==1 epilogue: stage clamped y16 in LDS (XOR-swizzled), read back half-rows,
// silu/rowmax during read-back, coalesced 16B global stores (no RMW, no bpermute).
template <int K, int N, int EPI>
__global__ __launch_bounds__(512, 2) void gemm8_i8_k(
    const int8_t* __restrict__ A, const int8_t* __restrict__ B,
    const float* __restrict__ rowInv, const float* __restrict__ invswp,
    short* __restrict__ Y16, float* __restrict__ rowmaxP,
    float* __restrict__ Out) {
  constexpr int NT = K / 128;
  constexpr int NBX = N / 256;
  __shared__ __align__(16) uint8_t lds[131072];

  const int t = threadIdx.x;
  const int wave = t >> 6;
  const int lane = t & 63;
  const int wr = wave >> 2;   // 0..1
  const int wc = wave & 3;    // 0..3
  const int l15 = lane & 15, l4 = lane >> 4;

  const int cpx = (int)gridDim.x >> 3;
  const int bid0 = blockIdx.x;
  const int bid = (bid0 & 7) * cpx + (bid0 >> 3);
  const int bx = bid % NBX, by = bid / NBX;
  const long arow0 = (long)by * 256;
  const long bcol0 = (long)bx * 256;

  const int8_t* Ablk = A + arow0 * K;
  const int8_t* Bblk = B + bcol0 * K;

  const int srow = t >> 3;
  const int scol = ((t & 7) ^ (srow & 7)) << 4;

  const int rAo = (wr * 128 + l15) * 128;
  const int rBo = (wc * 64 + l15) * 128;
  const int sw = (l15 & 7) << 4;
  const int cc0 = (l4 * 16) ^ sw;
  const int cc1 = (64 | (l4 * 16)) ^ sw;

  v4i acc[8][4] = {};
  v4i a_lo[4][2], a_hi[4][2], b_lo[2][2], b_hi[2][2];

#define STAGE(ktile_, part_)                                                      \
  do {                                                                            \
    const int kk = (ktile_);                                                      \
    if (kk < NT) {                                                                \
      uint8_t* d0 = lds + ((kk & 1) << 16) + ((part_) << 14) + (wave << 10);      \
      const int8_t* sp = ((part_) < 2) ? Ablk : Bblk;                             \
      const int8_t* s0 =                                                          \
          sp + (long)((((part_) & 1) << 7) + srow) * K + ((long)kk << 7) + scol;  \
      gload_lds16(s0, d0);                                                        \
      gload_lds16(s0 + ((long)K << 6), d0 + 8192);                                \
    }                                                                             \
  } while (0)

#define LGKM0 asm volatile("s_waitcnt lgkmcnt(0)" ::: "memory"); \
              __builtin_amdgcn_sched_barrier(0)
#define SB    __builtin_amdgcn_sched_barrier(0)

  STAGE(0, 0); STAGE(0, 1); STAGE(0, 2); STAGE(0, 3);
  STAGE(1, 0); STAGE(1, 1);
  asm volatile("s_waitcnt vmcnt(4)" ::: "memory");
  __builtin_amdgcn_s_barrier();

  for (int kt = 0; kt < NT; ++kt) {
    const uint8_t* sA = lds + ((kt & 1) << 16);
    const uint8_t* sB = sA + 32768;

#pragma unroll
    for (int m = 0; m < 4; ++m) {
      a_lo[m][0] = *(const v4i*)(sA + rAo + m * 2048 + cc0);
      a_lo[m][1] = *(const v4i*)(sA + rAo + m * 2048 + cc1);
    }
#pragma unroll
    for (int n = 0; n < 2; ++n) {
      b_lo[n][0] = *(const v4i*)(sB + rBo + n * 2048 + cc0);
      b_lo[n][1] = *(const v4i*)(sB + rBo + n * 2048 + cc1);
    }
    STAGE(kt + 1, 2);
    LGKM0;
#pragma unroll
    for (int m = 0; m < 4; ++m) {
      a_hi[m][0] = *(const v4i*)(sA + rAo + (m + 4) * 2048 + cc0);
      a_hi[m][1] = *(const v4i*)(sA + rAo + (m + 4) * 2048 + cc1);
    }
    STAGE(kt + 1, 3);
    SB;
    cluster<0, 0>(a_lo, b_lo, acc);
    LGKM0;
#pragma unroll
    for (int n = 0; n < 2; ++n) {
      b_hi[n][0] = *(const v4i*)(sB + rBo + (n + 2) * 2048 + cc0);
      b_hi[n][1] = *(const v4i*)(sB + rBo + (n + 2) * 2048 + cc1);
    }
    __builtin_amdgcn_s_barrier();
    STAGE(kt + 2, 0);
    SB;
    cluster<4, 0>(a_hi, b_lo, acc);
    LGKM0;
    STAGE(kt + 2, 1);
    SB;
    cluster<0, 2>(a_lo, b_hi, acc);
    cluster<4, 2>(a_hi, b_hi, acc);
    if (kt < NT - 2) {
      asm volatile("s_waitcnt vmcnt(4)" ::: "memory");
    } else if (kt == NT - 2) {
      asm volatile("s_waitcnt vmcnt(0)" ::: "memory");
    }
    __builtin_amdgcn_s_barrier();
  }

  const float invsw = invswp[0];
  if constexpr (EPI == 1) {
    __syncthreads();
    // Phase A: clamp + stage y16 into LDS short[256][256], byte XOR-swizzle (row&7)<<4
#pragma unroll
    for (int mi = 0; mi < 8; ++mi) {
#pragma unroll
      for (int r = 0; r < 4; ++r) {
        const int row = wr * 128 + mi * 16 + l4 * 4 + r;
#pragma unroll
        for (int ni = 0; ni < 4; ++ni) {
          int yi = acc[mi][ni][r];
          int ys = yi < -32767 ? -32767 : (yi > 32767 ? 32767 : yi);
          const int col = wc * 64 + ni * 16 + l15;
          const int byte = (row * 512 + col * 2) ^ ((row & 7) << 4);
          *(short*)(lds + byte) = (short)ys;
        }
      }
    }
    __syncthreads();
    // Phase B: 2 threads per row; each reads 128 contiguous shorts, computes
    // silu-max with the exact quant_h expression, stores 16B chunks to global.
    const int row = t >> 1;
    const int half = t & 1;
    const long grow = arow0 + row;
    const float c1v = rowInv[grow] * invsw;
    float mx = 0.f;
    short* gp = Y16 + grow * (long)DF + bcol0 + half * 128;
#pragma unroll
    for (int i = 0; i < 16; ++i) {
      const int byte = (row * 512 + half * 256 + i * 16) ^ ((row & 7) << 4);
      v8s yv = *(const v8s*)(lds + byte);
#pragma unroll
      for (int j = 0; j < 8; ++j) {
        float h = silu_f((float)yv[j] * c1v);
        mx = fmaxf(mx, fabsf(h));
      }
      *(v8s*)(gp + i * 8) = yv;
    }
    mx = fmaxf(mx, __shfl_xor(mx, 1, 64));
    if (half == 0) rowmaxP[grow * NBX + bx] = mx;
  } else {
#pragma unroll
    for (int mi = 0; mi < 8; ++mi) {
#pragma unroll
      for (int r = 0; r < 4; ++r) {
        const long grow = arow0 + wr * 128 + mi * 16 + l4 * 4 + r;
        const float c2 = rowInv[grow] * invsw;
#pragma unroll
        for (int ni = 0; ni < 4; ++ni)
          Out[grow * N + bcol0 + wc * 64 + ni * 16 + l15] = (float)acc[mi][ni][r] * c2;
      }
    }
  }
#undef STAGE
#undef LGKM0
#undef SB
}

// ---- quantize h per-token from int16 y ----
__global__ __launch_bounds__(256) void quant_h_k(const short* __restrict__ Y16,
                                                 const float* __restrict__ rowmaxP,
                                                 const float* __restrict__ inv_sx,
                                                 const float* __restrict__ sc,
                                                 int8_t* __restrict__ hq,
                                                 float* __restrict__ inv_sh) {
  const int t = threadIdx.x;
  const long row = blockIdx.x;
  __shared__ float smax_s;
  if (t < 64) {
    float m = (t < 32) ? rowmaxP[row * 32 + t] : 0.f;
#pragma unroll
    for (int d = 1; d < 64; d <<= 1) m = fmaxf(m, __shfl_xor(m, d, 64));
    if (t == 0) smax_s = m;
  }
  __syncthreads();
  const float scale = 127.0f / fmaxf(smax_s, 1e-5f);
  if (t == 0) inv_sh[row] = 1.0f / scale;
  const float c1 = inv_sx[row] * sc[1];
  const short4* yp = (const short4*)(Y16 + row * DF);
  int* op = (int*)(hq + row * DF);
#pragma unroll
  for (int b = 0; b < 8; ++b) {
    short4 s4 = yp[b * 256 + t];
    short vals[4] = {s4.x, s4.y, s4.z, s4.w};
    int q[4];
#pragma unroll
    for (int j = 0; j < 4; ++j) {
      float h = silu_f((float)vals[j] * c1);
      int qq = (int)rintf(h * scale);
      q[j] = qq < -128 ? -128 : (qq > 127 ? 127 : qq);
    }
    op[b * 256 + t] = (q[0] & 255) | ((q[1] & 255) << 8) | ((q[2] & 255) << 16) | ((q[3] & 255) << 24);
  }
}

extern "C" void kernel_launch(void* const* d_in, const int* in_sizes, int n_in,
                              void* d_out, int out_size, void* d_ws, size_t ws_size,
                              hipStream_t stream) {
  const float* x = (const float*)d_in[0];
  const float* W1 = (const float*)d_in[1];
  const float* W2 = (const float*)d_in[2];
  float* out = (float*)d_out;

  uint8_t* w = (uint8_t*)d_ws;
  float* sc = (float*)(w + 0);
  float* p1 = (float*)(w + 256);
  float* p2 = (float*)(w + 256 + 4096);
  float* inv_sx = (float*)(w + 8448);
  float* inv_sh = (float*)(w + 8448 + 65536);
  float* rowmaxP = (float*)(w + 8448 + 131072);
  uint8_t* w1q = w + 8448 + 131072 + 4194304;
  uint8_t* w2q = w1q + 16777216;
  uint8_t* xq = w2q + 16777216;
  uint8_t* hq = xq + 33554432;
  short* y16 = (short*)(hq + 134217728);

  abs_sum_k<<<1024, 256, 0, stream>>>(W1, p1);
  abs_sum_k<<<1024, 256, 0, stream>>>(W2, p2);
  finalize_scales_k<<<2, 256, 0, stream>>>(p1, p2, sc);
  tern_quant_k<<<16384, 256, 0, stream>>>(W1, (int8_t*)w1q, sc + 0);
  tern_quant_k<<<16384, 256, 0, stream>>>(W2, (int8_t*)w2q, sc + 2);
  act_quant_x_k<<<16384, 256, 0, stream>>>(x, (int8_t*)xq, inv_sx);
  gemm8_i8_k<2048, 8192, 1><<<2048, 512, 0, stream>>>(
      (const int8_t*)xq, (const int8_t*)w1q, inv_sx, sc + 1, y16, rowmaxP, nullptr);
  quant_h_k<<<16384, 256, 0, stream>>>(y16, rowmaxP, inv_sx, sc, (int8_t*)hq, inv_sh);
  gemm8_i8_k<8192, 2048, 0><<<512, 512, 0, stream>>>(
      (const int8_t*)hq, (const int8_t*)w2q, inv_sh, sc + 3, nullptr, nullptr, out);
}